// Round 4
// baseline (204.098 us; speedup 1.0000x reference)
//
#include <hip/hip_runtime.h>
#include <hip/hip_bf16.h>

#define T_DIM 64
#define NP 4096      /* N*C = 16*256 (n,c) pairs -> one block each */
#define D_OUTC 129

typedef float v2f __attribute__((ext_vector_type(2)));  // clang-native: OK for nontemporal builtin

// out[t,n,c,d] = w * sum_ch LIF( x[(.-s)%64] )[t],  s = min(round(delay), 63-argmax_t x)
// G[ch][t][s] precomputed for all 64 shifts in bf16 (abs threshold 0.6 allows it).
__global__ __launch_bounds__(256, 8) void jeffress_kernel(
    const float* __restrict__ input,        // (T, N, C, 2)
    const float* __restrict__ delay_param,  // (129, 1)
    const float* __restrict__ weight,       // scalar
    const float* __restrict__ u,            // (N, C, 129, 2)
    float* __restrict__ out)                // (T, N, C, 129)
{
    __shared__ float x_lds[2][64];
    __shared__ __hip_bfloat16 G[2][64 * 64];   // 16 KB: [ch][t][s]
    __shared__ int shifts[D_OUTC];             // s0 | s1<<16
    __shared__ int cap[2];                     // 63 - argmax_t

    const int p   = blockIdx.x;
    const int tid = threadIdx.x;
    const float DECAY = 0.6065306597126334f;   // exp(-1/2), same f32 value as reference

    // ---- phase 1+2 fused: load x, in-wave butterfly argmax (first occurrence) ----
    if (tid < 128) {
        int ch = tid >> 6, t = tid & 63;       // wave 0 = ch0, wave 1 = ch1; lane = t
        float xv = input[(t * NP + p) * 2 + ch];
        x_lds[ch][t] = xv;
        unsigned b = __float_as_uint(xv);
        b ^= (b & 0x80000000u) ? 0xffffffffu : 0x80000000u;  // total order for floats
        unsigned long long key = ((unsigned long long)b << 32) | (unsigned)(63 - t);
        #pragma unroll
        for (int m = 1; m < 64; m <<= 1) {
            unsigned long long o = __shfl_xor(key, m, 64);
            if (o > key) key = o;              // ties -> larger (63-t) -> first t
        }
        if ((tid & 63) == 0) cap[ch] = (int)(key & 0xffffffffull);  // = 63 - argmax
    }
    __syncthreads();

    if (tid < 128) {
        // ---- phase 3b (waves 0-1): LIF recurrence for all 64 shifts ----
        int ch = tid >> 6, s = tid & 63;
        const float* xs = x_lds[ch];
        __hip_bfloat16* g = G[ch];
        float v = 0.0f;
        #pragma unroll 4
        for (int t = 0; t < 64; ++t) {
            v = v * DECAY + xs[(t - s) & 63];  // permutation across lanes: conflict-free
            g[t * 64 + s] = __float2bfloat16(v);
        }
    } else {
        // ---- phase 3a (waves 2-3): per-d shifts (stoch. round + clamp), packed ----
        int c0 = cap[0], c1 = cap[1];
        for (int d = tid - 128; d < D_OUTC; d += 128) {
            float dp = delay_param[d];
            float b0 = fmaxf(dp, 0.0f), b1 = fmaxf(-dp, 0.0f);  // relu(cat([dp,-dp]))
            float2 uu = ((const float2*)u)[p * D_OUTC + d];
            float f0 = floorf(b0), f1 = floorf(b1);
            float r0 = (uu.x < b0 - f0) ? f0 + 1.0f : f0;
            float r1 = (uu.y < b1 - f1) ? f1 + 1.0f : f1;
            int s0 = (int)fminf(r0, (float)c0);
            int s1 = (int)fminf(r1, (float)c1);
            shifts[d] = s0 | (s1 << 16);
        }
    }
    __syncthreads();

    // ---- phase 4: one row (t) per wave per iter; parity-aligned float2 stores ----
    // Row byte-start = (t*NP+p)*516; mod 8 == 4*(p&1). Even p: pairs (2l,2l+1) are
    // 8B-aligned, leftover d=128. Odd p: scalar d=0, pairs (2l+1,2l+2) 8B-aligned.
    const float w = weight[0];
    const int wave = tid >> 6, lane = tid & 63;
    const int oddp = p & 1;
    const int d0 = oddp ? (2 * lane + 1) : (2 * lane);
    const int de = oddp ? 0 : 128;             // leftover element
    for (int t = wave; t < T_DIM; t += 4) {
        const __hip_bfloat16* Gt0 = &G[0][t * 64];
        const __hip_bfloat16* Gt1 = &G[1][t * 64];
        float* rowp = out + (size_t)(t * NP + p) * D_OUTC;
        int spA = shifts[d0];
        int spB = shifts[d0 + 1];
        float vA = w * (__bfloat162float(Gt0[spA & 0xffff]) + __bfloat162float(Gt1[spA >> 16]));
        float vB = w * (__bfloat162float(Gt0[spB & 0xffff]) + __bfloat162float(Gt1[spB >> 16]));
        v2f vv; vv.x = vA; vv.y = vB;
        __builtin_nontemporal_store(vv, reinterpret_cast<v2f*>(rowp + d0));
        if (lane == 0) {
            int spE = shifts[de];
            float vE = w * (__bfloat162float(Gt0[spE & 0xffff]) + __bfloat162float(Gt1[spE >> 16]));
            __builtin_nontemporal_store(vE, rowp + de);
        }
    }
}

extern "C" void kernel_launch(void* const* d_in, const int* in_sizes, int n_in,
                              void* d_out, int out_size, void* d_ws, size_t ws_size,
                              hipStream_t stream) {
    const float* input       = (const float*)d_in[0]; // (64,16,256,2)
    const float* delay_param = (const float*)d_in[1]; // (129,1)
    const float* weight      = (const float*)d_in[2]; // scalar
    const float* u           = (const float*)d_in[3]; // (16,256,129,2)
    float* out = (float*)d_out;                       // (64,16,256,129)

    jeffress_kernel<<<NP, 256, 0, stream>>>(input, delay_param, weight, u, out);
}

// Round 5
// 165.350 us; speedup vs baseline: 1.2343x; 1.2343x over previous
//
#include <hip/hip_runtime.h>
#include <hip/hip_bf16.h>

#define T_DIM 64
#define NP 4096      /* N*C = 16*256 (n,c) pairs -> one block each */
#define D_OUTC 129

typedef float v4f __attribute__((ext_vector_type(4)));

// out[t,n,c,d] = w * sum_ch LIF( x[(.-s)%64] )[t],  s = min(round(delay), 63-argmax_t x)
// G[ch][t][s] precomputed for all 64 shifts in bf16 (abs threshold 0.6 allows it).
__global__ __launch_bounds__(256, 8) void jeffress_kernel(
    const float* __restrict__ input,        // (T, N, C, 2)
    const float* __restrict__ delay_param,  // (129, 1)
    const float* __restrict__ weight,       // scalar
    const float* __restrict__ u,            // (N, C, 129, 2)
    float* __restrict__ out)                // (T, N, C, 129)
{
    __shared__ float x_lds[2][64];
    __shared__ __hip_bfloat16 G[2][64 * 64];   // 16 KB: [ch][t][s]
    __shared__ int shifts[D_OUTC];             // s0 | s1<<16
    __shared__ int cap[2];                     // 63 - argmax_t

    const int p   = blockIdx.x;
    const int tid = threadIdx.x;
    const int lane = tid & 63, wave = tid >> 6;
    const float DECAY = 0.6065306597126334f;   // exp(-1/2), same f32 value as reference

    // ---- phase 1+2 fused: load x, in-wave butterfly argmax (first occurrence) ----
    if (tid < 128) {
        int ch = wave, t = lane;               // wave 0 = ch0, wave 1 = ch1; lane = t
        float xv = input[(t * NP + p) * 2 + ch];
        x_lds[ch][t] = xv;
        unsigned b = __float_as_uint(xv);
        b ^= (b & 0x80000000u) ? 0xffffffffu : 0x80000000u;  // total order for floats
        unsigned long long key = ((unsigned long long)b << 32) | (unsigned)(63 - t);
        #pragma unroll
        for (int mm = 1; mm < 64; mm <<= 1) {
            unsigned long long o = __shfl_xor(key, mm, 64);
            if (o > key) key = o;              // ties -> larger (63-t) -> first t
        }
        if (lane == 0) cap[ch] = (int)(key & 0xffffffffull);  // = 63 - argmax
    }
    __syncthreads();

    if (tid < 128) {
        // ---- phase 3b (waves 0-1): LIF recurrence for all 64 shifts ----
        int ch = wave, s = lane;
        const float* xs = x_lds[ch];
        __hip_bfloat16* g = G[ch];
        float v = 0.0f;
        #pragma unroll 4
        for (int t = 0; t < 64; ++t) {
            v = v * DECAY + xs[(t - s) & 63];  // permutation across lanes: conflict-free
            g[t * 64 + s] = __float2bfloat16(v);
        }
    } else {
        // ---- phase 3a (waves 2-3): per-d shifts (stoch. round + clamp), packed ----
        int c0 = cap[0], c1 = cap[1];
        for (int d = tid - 128; d < D_OUTC; d += 128) {
            float dp = delay_param[d];
            float b0 = fmaxf(dp, 0.0f), b1 = fmaxf(-dp, 0.0f);  // relu(cat([dp,-dp]))
            float2 uu = ((const float2*)u)[p * D_OUTC + d];
            float f0 = floorf(b0), f1 = floorf(b1);
            float r0 = (uu.x < b0 - f0) ? f0 + 1.0f : f0;
            float r1 = (uu.y < b1 - f1) ? f1 + 1.0f : f1;
            int s0 = (int)fminf(r0, (float)c0);
            int s1 = (int)fminf(r1, (float)c1);
            shifts[d] = s0 | (s1 << 16);
        }
    }
    __syncthreads();

    // ---- phase 4: aligned float4 body + <=5 scalar extras per 516B row ----
    // Row byte-start mod 16 = 4*(p&3). Head a=(4-p%4)&3 floats brings us to a 16B
    // boundary; body = m float4 (m=31|32); extras = head + tail (e=129-4m, 1 or 5).
    const float w = weight[0];
    const int a = (4 - (p & 3)) & 3;
    const int m = (D_OUTC - a) >> 2;
    const int e = D_OUTC - 4 * m;
    const bool isBody  = lane < m;
    const bool isExtra = (lane >= m) && (lane - m < e);

    // hoist this thread's shift pairs into registers (one-time LDS read)
    int o00=0,o01=0,o10=0,o11=0,o20=0,o21=0,o30=0,o31=0; // byte offsets 2*s into G rows
    int dE = 0;
    if (isBody) {
        int dd = a + 4 * lane;
        int p0 = shifts[dd], p1 = shifts[dd+1], p2 = shifts[dd+2], p3 = shifts[dd+3];
        o00 = (p0 & 0xffff) * 2; o01 = (p0 >> 16) * 2;
        o10 = (p1 & 0xffff) * 2; o11 = (p1 >> 16) * 2;
        o20 = (p2 & 0xffff) * 2; o21 = (p2 >> 16) * 2;
        o30 = (p3 & 0xffff) * 2; o31 = (p3 >> 16) * 2;
    } else if (isExtra) {
        int j = lane - m;
        dE = (j < a) ? j : 4 * m + j;          // head floats then tail floats
        int pe = shifts[dE];
        o00 = (pe & 0xffff) * 2; o01 = (pe >> 16) * 2;
    }

    const char* G0b = (const char*)&G[0][0];
    const char* G1b = (const char*)&G[1][0];
    for (int t = wave; t < T_DIM; t += 4) {
        const char* r0 = G0b + t * 128;        // 64 bf16 per (ch,t) row
        const char* r1 = G1b + t * 128;
        float* rowp = out + (size_t)(t * NP + p) * D_OUTC;
        if (isBody) {
            v4f v;
            v.x = w * (__bfloat162float(*(const __hip_bfloat16*)(r0 + o00)) +
                       __bfloat162float(*(const __hip_bfloat16*)(r1 + o01)));
            v.y = w * (__bfloat162float(*(const __hip_bfloat16*)(r0 + o10)) +
                       __bfloat162float(*(const __hip_bfloat16*)(r1 + o11)));
            v.z = w * (__bfloat162float(*(const __hip_bfloat16*)(r0 + o20)) +
                       __bfloat162float(*(const __hip_bfloat16*)(r1 + o21)));
            v.w = w * (__bfloat162float(*(const __hip_bfloat16*)(r0 + o30)) +
                       __bfloat162float(*(const __hip_bfloat16*)(r1 + o31)));
            *reinterpret_cast<v4f*>(rowp + a + 4 * lane) = v;   // 16B-aligned, via L2
        }
        if (isExtra) {
            float vE = w * (__bfloat162float(*(const __hip_bfloat16*)(r0 + o00)) +
                            __bfloat162float(*(const __hip_bfloat16*)(r1 + o01)));
            rowp[dE] = vE;
        }
    }
}

extern "C" void kernel_launch(void* const* d_in, const int* in_sizes, int n_in,
                              void* d_out, int out_size, void* d_ws, size_t ws_size,
                              hipStream_t stream) {
    const float* input       = (const float*)d_in[0]; // (64,16,256,2)
    const float* delay_param = (const float*)d_in[1]; // (129,1)
    const float* weight      = (const float*)d_in[2]; // scalar
    const float* u           = (const float*)d_in[3]; // (16,256,129,2)
    float* out = (float*)d_out;                       // (64,16,256,129)

    jeffress_kernel<<<NP, 256, 0, stream>>>(input, delay_param, weight, u, out);
}

// Round 6
// 157.316 us; speedup vs baseline: 1.2974x; 1.0511x over previous
//
#include <hip/hip_runtime.h>
#include <hip/hip_bf16.h>

#define T_DIM 64
#define NP 4096      /* N*C = 16*256 (n,c) pairs -> one block each */
#define D_OUTC 129

typedef float v4f __attribute__((ext_vector_type(4)));

static __device__ __forceinline__ float bfld(const char* p) {
    return __bfloat162float(*(const __hip_bfloat16*)p);
}

// out[t,n,c,d] = w * sum_ch LIF( x[(.-s)%64] )[t],  s = min(round(delay), 63-argmax_t x)
// G[ch][t][s] in bf16; byte addr of (ch,t,s) = ch*8192 + t*128 + 2*s.
// Key structural fact (delay = relu(+-(d-64))): for d<=64 s0==0, for d>=64 s1==0,
// so each output needs ONE varying gather + one wave-uniform term h_ch[t]=G[ch][t][0].
// A generic "both" fallback (flag bit7) keeps correctness for arbitrary delay data.
__global__ __launch_bounds__(256, 8) void jeffress_kernel(
    const float* __restrict__ input,        // (T, N, C, 2)
    const float* __restrict__ delay_param,  // (129, 1)
    const float* __restrict__ weight,       // scalar
    const float* __restrict__ u,            // (N, C, 129, 2)
    float* __restrict__ out)                // (T, N, C, 129)
{
    __shared__ float x_lds[2][64];
    __shared__ __hip_bfloat16 G[2][64 * 64];   // 16 KB
    __shared__ int shifts[D_OUTC];             // packed: s_var|chan<<6|both<<7|s_other<<8
    __shared__ int cap[2];                     // 63 - argmax_t

    // XCD swizzle: blockIdx%8 = XCD; give each XCD a contiguous 512-range of p so
    // 516B row-boundary lines merge in ONE XCD's L2 (kills partial-line HBM RMW).
    const int p   = ((blockIdx.x & 7) << 9) | (blockIdx.x >> 3);
    const int tid = threadIdx.x;
    const int lane = tid & 63, wave = tid >> 6;
    const float DECAY = 0.6065306597126334f;   // exp(-1/2), same f32 value as reference

    // ---- phase 1+2 fused: load x, in-wave butterfly argmax (first occurrence) ----
    if (tid < 128) {
        int ch = wave, t = lane;
        float xv = input[(t * NP + p) * 2 + ch];
        x_lds[ch][t] = xv;
        unsigned b = __float_as_uint(xv);
        b ^= (b & 0x80000000u) ? 0xffffffffu : 0x80000000u;  // total order for floats
        unsigned long long key = ((unsigned long long)b << 32) | (unsigned)(63 - t);
        #pragma unroll
        for (int mm = 1; mm < 64; mm <<= 1) {
            unsigned long long o = __shfl_xor(key, mm, 64);
            if (o > key) key = o;              // ties -> larger (63-t) -> first t
        }
        if (lane == 0) cap[ch] = (int)(key & 0xffffffffull);  // = 63 - argmax
    }
    __syncthreads();

    if (tid < 128) {
        // ---- phase 3b (waves 0-1): LIF recurrence for all 64 shifts ----
        int ch = wave, s = lane;
        const float* xs = x_lds[ch];
        __hip_bfloat16* g = G[ch];
        float v = 0.0f;
        #pragma unroll 4
        for (int t = 0; t < 64; ++t) {
            v = v * DECAY + xs[(t - s) & 63];  // lane permutation: conflict-free
            g[t * 64 + s] = __float2bfloat16(v);
        }
    } else {
        // ---- phase 3a (waves 2-3): per-d shifts -> packed gather descriptors ----
        int c0 = cap[0], c1 = cap[1];
        for (int d = tid - 128; d < D_OUTC; d += 128) {
            float dp = delay_param[d];
            float b0 = fmaxf(dp, 0.0f), b1 = fmaxf(-dp, 0.0f);  // relu(cat([dp,-dp]))
            float2 uu = ((const float2*)u)[p * D_OUTC + d];
            float f0 = floorf(b0), f1 = floorf(b1);
            float r0 = (uu.x < b0 - f0) ? f0 + 1.0f : f0;
            float r1 = (uu.y < b1 - f1) ? f1 + 1.0f : f1;
            int s0 = (int)fminf(r0, (float)c0);
            int s1 = (int)fminf(r1, (float)c1);
            int entry;
            if (s0 == 0)      entry = s1 | (1 << 6);             // gather ch1, + h0
            else if (s1 == 0) entry = s0;                        // gather ch0, + h1
            else              entry = s0 | (1 << 7) | (s1 << 8); // both gathers
            shifts[d] = entry;
        }
    }
    __syncthreads();

    // ---- phase 4: 1 gather per element + uniform term; aligned float4 stores ----
    const float w = weight[0];
    const int a = (4 - (p & 3)) & 3;           // head floats to reach 16B boundary
    const int m = (D_OUTC - a) >> 2;           // float4 body count (31 or 32)
    const int e = D_OUTC - 4 * m;              // extras: head + tail (1 or 5)
    const bool isBody  = lane < m;
    const bool isExtra = (lane >= m) && (lane - m < e);

    int o0=0,o1=0,o2=0,o3=0;       // varying-gather byte offsets (chan*8192 + 2*s)
    int u0=0,u1=0,u2=0,u3=0;       // 1 -> uniform term is h0, else h1
    int q0=0,q1=0,q2=0,q3=0;       // both-flag
    int a20=0,a21=0,a22=0,a23=0;   // second-gather byte offsets (ch1)
    int dE = 0;
    if (isBody) {
        int dd = a + 4 * lane;
        int e0 = shifts[dd], e1 = shifts[dd+1], e2 = shifts[dd+2], e3 = shifts[dd+3];
        o0 = ((e0 >> 6) & 1) * 8192 + (e0 & 63) * 2; u0 = (e0 >> 6) & 1; q0 = (e0 >> 7) & 1; a20 = 8192 + ((e0 >> 8) & 63) * 2;
        o1 = ((e1 >> 6) & 1) * 8192 + (e1 & 63) * 2; u1 = (e1 >> 6) & 1; q1 = (e1 >> 7) & 1; a21 = 8192 + ((e1 >> 8) & 63) * 2;
        o2 = ((e2 >> 6) & 1) * 8192 + (e2 & 63) * 2; u2 = (e2 >> 6) & 1; q2 = (e2 >> 7) & 1; a22 = 8192 + ((e2 >> 8) & 63) * 2;
        o3 = ((e3 >> 6) & 1) * 8192 + (e3 & 63) * 2; u3 = (e3 >> 6) & 1; q3 = (e3 >> 7) & 1; a23 = 8192 + ((e3 >> 8) & 63) * 2;
    } else if (isExtra) {
        int j = lane - m;
        dE = (j < a) ? j : 4 * m + j;          // head floats then tail floats
        int ee = shifts[dE];
        o0 = ((ee >> 6) & 1) * 8192 + (ee & 63) * 2; u0 = (ee >> 6) & 1; q0 = (ee >> 7) & 1; a20 = 8192 + ((ee >> 8) & 63) * 2;
    }
    const bool anyboth = __ballot((isBody | isExtra) ? (q0 | q1 | q2 | q3) : 0) != 0ull;

    const char* Gb = (const char*)&G[0][0];
    for (int t = wave; t < T_DIM; t += 4) {
        const char* bt = Gb + t * 128;         // channel-0 row; ch1 at +8192
        float h0 = bfld(bt);                   // G[0][t][0], broadcast read
        float h1 = bfld(bt + 8192);            // G[1][t][0]
        float* rowp = out + (size_t)(t * NP + p) * D_OUTC;
        if (isBody) {
            float g0v = bfld(bt + o0), g1v = bfld(bt + o1);
            float g2v = bfld(bt + o2), g3v = bfld(bt + o3);
            float v0 = g0v + (u0 ? h0 : h1);
            float v1 = g1v + (u1 ? h0 : h1);
            float v2 = g2v + (u2 ? h0 : h1);
            float v3 = g3v + (u3 ? h0 : h1);
            if (anyboth) {                     // generic fallback, never taken here
                if (q0) v0 = g0v + bfld(bt + a20);
                if (q1) v1 = g1v + bfld(bt + a21);
                if (q2) v2 = g2v + bfld(bt + a22);
                if (q3) v3 = g3v + bfld(bt + a23);
            }
            v4f v; v.x = w * v0; v.y = w * v1; v.z = w * v2; v.w = w * v3;
            *reinterpret_cast<v4f*>(rowp + a + 4 * lane) = v;   // 16B-aligned
        }
        if (isExtra) {
            float gv = bfld(bt + o0);
            float vE = gv + (u0 ? h0 : h1);
            if (anyboth && q0) vE = gv + bfld(bt + a20);
            rowp[dE] = w * vE;
        }
    }
}

extern "C" void kernel_launch(void* const* d_in, const int* in_sizes, int n_in,
                              void* d_out, int out_size, void* d_ws, size_t ws_size,
                              hipStream_t stream) {
    const float* input       = (const float*)d_in[0]; // (64,16,256,2)
    const float* delay_param = (const float*)d_in[1]; // (129,1)
    const float* weight      = (const float*)d_in[2]; // scalar
    const float* u           = (const float*)d_in[3]; // (16,256,129,2)
    float* out = (float*)d_out;                       // (64,16,256,129)

    jeffress_kernel<<<NP, 256, 0, stream>>>(input, delay_param, weight, u, out);
}